// Round 5
// baseline (166.454 us; speedup 1.0000x reference)
//
#include <hip/hip_runtime.h>

constexpr int PPB = 16;  // consecutive points per block: sequential 61KB store
                         // stream per block, 8192 blocks

__global__ __launch_bounds__(256) void GraphProjection_57483842289710_kernel(
    const float* __restrict__ coord,
    const float* __restrict__ f56,
    const float* __restrict__ f28,
    const float* __restrict__ f14,
    const float* __restrict__ f7,
    float* __restrict__ out,
    int n)
{
    const int t = threadIdx.x;

    // ---- loop-invariant per-thread level params (selected ONCE) ----
    const int ch = 4 * t;                 // channels ch..ch+3 of the 960
    const float* f; int C, H; float inv;
    if (ch < 64)       { f = f56 + ch;         C = 64;  H = 56; inv = 0.25f;    }
    else if (ch < 192) { f = f28 + (ch - 64);  C = 128; H = 28; inv = 0.125f;   }
    else if (ch < 448) { f = f14 + (ch - 192); C = 256; H = 14; inv = 0.0625f;  }
    else               { f = f7  + (ch - 448); C = 512; H = 7;  inv = 0.03125f; }

    const int p0 = blockIdx.x * PPB;
    const int pend = min(p0 + PPB, n);

    #pragma unroll 2
    for (int p = p0; p < pend; ++p) {
        float* __restrict__ orow = out + (size_t)p * 963;

        const float X = coord[p * 3 + 0];
        const float Y = coord[p * 3 + 1];
        const float Z = coord[p * 3 + 2];

        // one IEEE divide shared by h and w (verified absmax 0.0156 << 0.149)
        const float rz = 1.0f / (-Z);
        float h = 250.0f * (-Y) * rz + 112.0f;
        float w = 250.0f * X  * rz + 112.0f;
        h = fminf(fmaxf(h, 0.0f), 223.0f);
        w = fminf(fmaxf(w, 0.0f), 223.0f);

        if (t < 240) {
            const float x = h * inv, y = w * inv;
            const float x1 = floorf(x), x2 = ceilf(x);
            const float y1 = floorf(y), y2 = ceilf(y);
            const int xi1 = min(max((int)x1, 0), H - 1);
            const int xi2 = min(max((int)x2, 0), H - 1);
            const int yi1 = min(max((int)y1, 0), H - 1);
            const int yi2 = min(max((int)y2, 0), H - 1);
            const float w11 = (x2 - x) * (y2 - y);
            const float w21 = (x - x1) * (y2 - y);
            const float w12 = (x2 - x) * (y - y1);
            const float w22 = (x - x1) * (y - y1);

            const int r1 = xi1 * H, r2 = xi2 * H;
            const float4 a = *reinterpret_cast<const float4*>(f + (r1 + yi1) * C);
            const float4 b = *reinterpret_cast<const float4*>(f + (r2 + yi1) * C);
            const float4 d = *reinterpret_cast<const float4*>(f + (r1 + yi2) * C);
            const float4 e = *reinterpret_cast<const float4*>(f + (r2 + yi2) * C);

            float rx = w11 * a.x + w21 * b.x + w12 * d.x + w22 * e.x;
            float ry = w11 * a.y + w21 * b.y + w12 * d.y + w22 * e.y;
            float rz2 = w11 * a.z + w21 * b.z + w12 * d.z + w22 * e.z;
            float rw = w11 * a.w + w21 * b.w + w12 * d.w + w22 * e.w;

            // Non-temporal: do NOT allocate the 505MB write stream in L2 —
            // keeps the 1.5MB feature maps L2-resident for the gathers.
            float* dst = orow + 3 + ch;
            __builtin_nontemporal_store(rx,  dst + 0);
            __builtin_nontemporal_store(ry,  dst + 1);
            __builtin_nontemporal_store(rz2, dst + 2);
            __builtin_nontemporal_store(rw,  dst + 3);
        } else if (t < 243) {
            __builtin_nontemporal_store(coord[p * 3 + (t - 240)], orow + (t - 240));
        }
    }
}

extern "C" void kernel_launch(void* const* d_in, const int* in_sizes, int n_in,
                              void* d_out, int out_size, void* d_ws, size_t ws_size,
                              hipStream_t stream) {
    const float* coord = (const float*)d_in[0];
    const float* f56   = (const float*)d_in[1];
    const float* f28   = (const float*)d_in[2];
    const float* f14   = (const float*)d_in[3];
    const float* f7    = (const float*)d_in[4];
    float* out = (float*)d_out;

    int n = in_sizes[0] / 3;  // 131072 points
    int grid = (n + PPB - 1) / PPB;  // 8192 blocks of 16 consecutive points
    GraphProjection_57483842289710_kernel<<<grid, 256, 0, stream>>>(
        coord, f56, f28, f14, f7, out, n);
}

// Round 6
// 165.989 us; speedup vs baseline: 1.0028x; 1.0028x over previous
//
#include <hip/hip_runtime.h>

constexpr int PPB = 16;  // consecutive points per block: sequential 61KB store
                         // stream per block, 8192 blocks

typedef float f4v __attribute__((ext_vector_type(4)));  // 16B vector, 4B-aligned ok

__global__ __launch_bounds__(256) void GraphProjection_57483842289710_kernel(
    const float* __restrict__ coord,
    const float* __restrict__ f56,
    const float* __restrict__ f28,
    const float* __restrict__ f14,
    const float* __restrict__ f7,
    float* __restrict__ out,
    int n)
{
    const int t = threadIdx.x;

    // ---- loop-invariant per-thread level params (selected ONCE) ----
    const int ch = 4 * t;                 // channels ch..ch+3 of the 960
    const float* f; int C, H; float inv;
    if (ch < 64)       { f = f56 + ch;         C = 64;  H = 56; inv = 0.25f;    }
    else if (ch < 192) { f = f28 + (ch - 64);  C = 128; H = 28; inv = 0.125f;   }
    else if (ch < 448) { f = f14 + (ch - 192); C = 256; H = 14; inv = 0.0625f;  }
    else               { f = f7  + (ch - 448); C = 512; H = 7;  inv = 0.03125f; }

    const int p0 = blockIdx.x * PPB;
    const int pend = min(p0 + PPB, n);

    #pragma unroll 2
    for (int p = p0; p < pend; ++p) {
        float* __restrict__ orow = out + (size_t)p * 963;

        const float X = coord[p * 3 + 0];
        const float Y = coord[p * 3 + 1];
        const float Z = coord[p * 3 + 2];

        // one IEEE divide shared by h and w (verified absmax 0.0156 << 0.149)
        const float rz = 1.0f / (-Z);
        float h = 250.0f * (-Y) * rz + 112.0f;
        float w = 250.0f * X  * rz + 112.0f;
        h = fminf(fmaxf(h, 0.0f), 223.0f);
        w = fminf(fmaxf(w, 0.0f), 223.0f);

        if (t < 240) {
            const float x = h * inv, y = w * inv;
            const float x1 = floorf(x), x2 = ceilf(x);
            const float y1 = floorf(y), y2 = ceilf(y);
            const int xi1 = min(max((int)x1, 0), H - 1);
            const int xi2 = min(max((int)x2, 0), H - 1);
            const int yi1 = min(max((int)y1, 0), H - 1);
            const int yi2 = min(max((int)y2, 0), H - 1);
            const float w11 = (x2 - x) * (y2 - y);
            const float w21 = (x - x1) * (y2 - y);
            const float w12 = (x2 - x) * (y - y1);
            const float w22 = (x - x1) * (y - y1);

            const int r1 = xi1 * H, r2 = xi2 * H;
            const float4 a = *reinterpret_cast<const float4*>(f + (r1 + yi1) * C);
            const float4 b = *reinterpret_cast<const float4*>(f + (r2 + yi1) * C);
            const float4 d = *reinterpret_cast<const float4*>(f + (r1 + yi2) * C);
            const float4 e = *reinterpret_cast<const float4*>(f + (r2 + yi2) * C);

            f4v r;
            r.x = w11 * a.x + w21 * b.x + w12 * d.x + w22 * e.x;
            r.y = w11 * a.y + w21 * b.y + w12 * d.y + w22 * e.y;
            r.z = w11 * a.z + w21 * b.z + w12 * d.z + w22 * e.z;
            r.w = w11 * a.w + w21 * b.w + w12 * d.w + w22 * e.w;

            // Single 16B non-temporal store: one global_store_dwordx4 with nt —
            // same width as round-4's winner, only the cache policy differs.
            __builtin_nontemporal_store(r, reinterpret_cast<f4v*>(orow + 3 + ch));
        } else if (t < 243) {
            __builtin_nontemporal_store(coord[p * 3 + (t - 240)], orow + (t - 240));
        }
    }
}

extern "C" void kernel_launch(void* const* d_in, const int* in_sizes, int n_in,
                              void* d_out, int out_size, void* d_ws, size_t ws_size,
                              hipStream_t stream) {
    const float* coord = (const float*)d_in[0];
    const float* f56   = (const float*)d_in[1];
    const float* f28   = (const float*)d_in[2];
    const float* f14   = (const float*)d_in[3];
    const float* f7    = (const float*)d_in[4];
    float* out = (float*)d_out;

    int n = in_sizes[0] / 3;  // 131072 points
    int grid = (n + PPB - 1) / PPB;  // 8192 blocks of 16 consecutive points
    GraphProjection_57483842289710_kernel<<<grid, 256, 0, stream>>>(
        coord, f56, f28, f14, f7, out, n);
}

// Round 7
// 138.759 us; speedup vs baseline: 1.1996x; 1.1962x over previous
//
#include <hip/hip_runtime.h>

constexpr int PPB = 16;  // consecutive points per block
constexpr int N56 = 56*56*64;    // 200704
constexpr int N28 = 28*28*128;   // 100352
constexpr int N14 = 14*14*256;   //  50176
constexpr int N7  = 7*7*512;     //  25088
constexpr int NTOT = N56 + N28 + N14 + N7;  // 376320

typedef float    f4v __attribute__((ext_vector_type(4)));
typedef _Float16 h4v __attribute__((ext_vector_type(4)));

// ---- tiny pass: fp32 features -> fp16 in d_ws (row layout unchanged) ----
__global__ __launch_bounds__(256) void convert_feats_kernel(
    const float* __restrict__ f56, const float* __restrict__ f28,
    const float* __restrict__ f14, const float* __restrict__ f7,
    _Float16* __restrict__ ws)
{
    int idx = blockIdx.x * 256 + threadIdx.x;
    if (idx >= NTOT) return;
    float v;
    if (idx < N56)             v = f56[idx];
    else if (idx < N56+N28)    v = f28[idx - N56];
    else if (idx < N56+N28+N14) v = f14[idx - (N56+N28)];
    else                       v = f7[idx - (N56+N28+N14)];
    ws[idx] = (_Float16)v;   // RNE
}

// ---- hot kernel: fp16 gathers (8B/texel), fp32 math, fp32 dwordx4 stores ----
__global__ __launch_bounds__(256) void GraphProjection_57483842289710_kernel(
    const float* __restrict__ coord,
    const _Float16* __restrict__ ws,
    float* __restrict__ out,
    int n)
{
    const int t = threadIdx.x;
    const int ch = 4 * t;
    const _Float16* f; int C, H; float inv;
    if (ch < 64)       { f = ws + ch;                     C = 64;  H = 56; inv = 0.25f;    }
    else if (ch < 192) { f = ws + N56 + (ch - 64);        C = 128; H = 28; inv = 0.125f;   }
    else if (ch < 448) { f = ws + N56+N28 + (ch - 192);   C = 256; H = 14; inv = 0.0625f;  }
    else               { f = ws + N56+N28+N14 + (ch-448); C = 512; H = 7;  inv = 0.03125f; }

    const int p0 = blockIdx.x * PPB;
    const int pend = min(p0 + PPB, n);

    #pragma unroll 2
    for (int p = p0; p < pend; ++p) {
        float* __restrict__ orow = out + (size_t)p * 963;

        const float X = coord[p * 3 + 0];
        const float Y = coord[p * 3 + 1];
        const float Z = coord[p * 3 + 2];

        const float rz = 1.0f / (-Z);
        float h = 250.0f * (-Y) * rz + 112.0f;
        float w = 250.0f * X  * rz + 112.0f;
        h = fminf(fmaxf(h, 0.0f), 223.0f);
        w = fminf(fmaxf(w, 0.0f), 223.0f);

        if (t < 240) {
            const float x = h * inv, y = w * inv;
            const float x1 = floorf(x), x2 = ceilf(x);
            const float y1 = floorf(y), y2 = ceilf(y);
            const int xi1 = min(max((int)x1, 0), H - 1);
            const int xi2 = min(max((int)x2, 0), H - 1);
            const int yi1 = min(max((int)y1, 0), H - 1);
            const int yi2 = min(max((int)y2, 0), H - 1);
            const float w11 = (x2 - x) * (y2 - y);
            const float w21 = (x - x1) * (y2 - y);
            const float w12 = (x2 - x) * (y - y1);
            const float w22 = (x - x1) * (y - y1);

            const int r1 = xi1 * H, r2 = xi2 * H;
            // 8B-aligned fp16 quad loads (offsets are multiples of 4 halves)
            const h4v a = *reinterpret_cast<const h4v*>(f + (r1 + yi1) * C);
            const h4v b = *reinterpret_cast<const h4v*>(f + (r2 + yi1) * C);
            const h4v d = *reinterpret_cast<const h4v*>(f + (r1 + yi2) * C);
            const h4v e = *reinterpret_cast<const h4v*>(f + (r2 + yi2) * C);

            f4v r;
            r.x = w11*(float)a.x + w21*(float)b.x + w12*(float)d.x + w22*(float)e.x;
            r.y = w11*(float)a.y + w21*(float)b.y + w12*(float)d.y + w22*(float)e.y;
            r.z = w11*(float)a.z + w21*(float)b.z + w12*(float)d.z + w22*(float)e.z;
            r.w = w11*(float)a.w + w21*(float)b.w + w12*(float)d.w + w22*(float)e.w;

            *reinterpret_cast<f4v*>(orow + 3 + ch) = r;  // normal (write-allocate) store
        } else if (t < 243) {
            orow[t - 240] = coord[p * 3 + (t - 240)];
        }
    }
}

// ---- fp32 fallback (round-4 winner) if ws_size is too small ----
__global__ __launch_bounds__(256) void proj_f32_kernel(
    const float* __restrict__ coord,
    const float* __restrict__ f56, const float* __restrict__ f28,
    const float* __restrict__ f14, const float* __restrict__ f7,
    float* __restrict__ out, int n)
{
    const int t = threadIdx.x;
    const int ch = 4 * t;
    const float* f; int C, H; float inv;
    if (ch < 64)       { f = f56 + ch;         C = 64;  H = 56; inv = 0.25f;    }
    else if (ch < 192) { f = f28 + (ch - 64);  C = 128; H = 28; inv = 0.125f;   }
    else if (ch < 448) { f = f14 + (ch - 192); C = 256; H = 14; inv = 0.0625f;  }
    else               { f = f7  + (ch - 448); C = 512; H = 7;  inv = 0.03125f; }

    const int p0 = blockIdx.x * PPB;
    const int pend = min(p0 + PPB, n);

    #pragma unroll 2
    for (int p = p0; p < pend; ++p) {
        float* __restrict__ orow = out + (size_t)p * 963;
        const float X = coord[p*3+0], Y = coord[p*3+1], Z = coord[p*3+2];
        const float rz = 1.0f / (-Z);
        float h = 250.0f * (-Y) * rz + 112.0f;
        float w = 250.0f * X  * rz + 112.0f;
        h = fminf(fmaxf(h, 0.0f), 223.0f);
        w = fminf(fmaxf(w, 0.0f), 223.0f);
        if (t < 240) {
            const float x = h * inv, y = w * inv;
            const float x1 = floorf(x), x2 = ceilf(x);
            const float y1 = floorf(y), y2 = ceilf(y);
            const int xi1 = min(max((int)x1, 0), H - 1);
            const int xi2 = min(max((int)x2, 0), H - 1);
            const int yi1 = min(max((int)y1, 0), H - 1);
            const int yi2 = min(max((int)y2, 0), H - 1);
            const float w11 = (x2-x)*(y2-y), w21 = (x-x1)*(y2-y);
            const float w12 = (x2-x)*(y-y1), w22 = (x-x1)*(y-y1);
            const int r1 = xi1*H, r2 = xi2*H;
            const float4 a = *reinterpret_cast<const float4*>(f + (r1+yi1)*C);
            const float4 b = *reinterpret_cast<const float4*>(f + (r2+yi1)*C);
            const float4 d = *reinterpret_cast<const float4*>(f + (r1+yi2)*C);
            const float4 e = *reinterpret_cast<const float4*>(f + (r2+yi2)*C);
            f4v r;
            r.x = w11*a.x + w21*b.x + w12*d.x + w22*e.x;
            r.y = w11*a.y + w21*b.y + w12*d.y + w22*e.y;
            r.z = w11*a.z + w21*b.z + w12*d.z + w22*e.z;
            r.w = w11*a.w + w21*b.w + w12*d.w + w22*e.w;
            *reinterpret_cast<f4v*>(orow + 3 + ch) = r;
        } else if (t < 243) {
            orow[t - 240] = coord[p*3 + (t-240)];
        }
    }
}

extern "C" void kernel_launch(void* const* d_in, const int* in_sizes, int n_in,
                              void* d_out, int out_size, void* d_ws, size_t ws_size,
                              hipStream_t stream) {
    const float* coord = (const float*)d_in[0];
    const float* f56   = (const float*)d_in[1];
    const float* f28   = (const float*)d_in[2];
    const float* f14   = (const float*)d_in[3];
    const float* f7    = (const float*)d_in[4];
    float* out = (float*)d_out;

    int n = in_sizes[0] / 3;  // 131072 points
    int grid = (n + PPB - 1) / PPB;

    if (ws_size >= (size_t)NTOT * sizeof(_Float16)) {
        _Float16* ws = (_Float16*)d_ws;
        convert_feats_kernel<<<(NTOT + 255) / 256, 256, 0, stream>>>(f56, f28, f14, f7, ws);
        GraphProjection_57483842289710_kernel<<<grid, 256, 0, stream>>>(coord, ws, out, n);
    } else {
        proj_f32_kernel<<<grid, 256, 0, stream>>>(coord, f56, f28, f14, f7, out, n);
    }
}